// Round 9
// baseline (262.830 us; speedup 1.0000x reference)
//
#include <hip/hip_runtime.h>
#include <hip/hip_bf16.h>
#include <stdint.h>

// Shapes (fixed): B=4, S=2048, D_MODEL=D_K=D_V=1024
#define SEQ   2048
#define DM    1024
#define NBAT  4

typedef __attribute__((ext_vector_type(8))) short  short8;   // 8 bf16 = 4 VGPRs (MFMA A/B frag)
typedef __attribute__((ext_vector_type(4))) float  floatx4;  // MFMA C/D frag

__device__ __forceinline__ unsigned short f2b(float f) {
    __hip_bfloat16 h = __float2bfloat16(f);
    unsigned short r;
    __builtin_memcpy(&r, &h, 2);
    return r;
}

__device__ __forceinline__ ushort4 pack4(float a, float b, float c, float d) {
    ushort4 u; u.x = f2b(a); u.y = f2b(b); u.z = f2b(c); u.w = f2b(d); return u;
}

// async global->LDS, 16B per lane. dst must be wave-uniform base (lane*16 added by HW).
__device__ __forceinline__ void gload16(const void* g, void* s) {
    __builtin_amdgcn_global_load_lds(
        (const __attribute__((address_space(1))) unsigned int*)(uintptr_t)g,
        (__attribute__((address_space(3))) unsigned int*)(uintptr_t)s,
        16, 0, 0);
}

// One fused prep dispatch: x cast (blocks 0..8191), Wq/Wk/Wv cast into contiguous
// wall[3*DM,DM] (blocks 8192..11263), rowsum zero (blocks 11264..11295).
__global__ void prep(const float4* __restrict__ x,
                     const float4* __restrict__ w0, const float4* __restrict__ w1,
                     const float4* __restrict__ w2,
                     ushort4* __restrict__ xb, ushort4* __restrict__ wall,
                     float* __restrict__ rsum)
{
    const int b = blockIdx.x;
    const int t = threadIdx.x;
    if (b < 8192) {
        const int i = b * 256 + t;
        float4 f = x[i];
        xb[i] = pack4(f.x, f.y, f.z, f.w);
    } else if (b < 11264) {
        const int idx  = b - 8192;
        const int wsel = idx >> 10;
        const int i    = (idx & 1023) * 256 + t;
        const float4* src = (wsel == 0) ? w0 : (wsel == 1) ? w1 : w2;
        float4 f = src[i];
        wall[(size_t)wsel * 262144 + i] = pack4(f.x, f.y, f.z, f.w);
    } else {
        rsum[(b - 11264) * 256 + t] = 0.f;
    }
}

// ---------------------------------------------------------------------------
// R9: fine-phase 256x256 core (m196/m201-faithful; R8 lesson: every coarse
// structure pins at 30% MfmaUtil, time scales with work -> the fine per-phase
// interleave with counted vmcnt at EVERY phase is the one untested lever).
// BM=BN=256, BK=64 split into K-halves of 32; 8 waves (2M x 4N, wave 128x64).
// LDS = 3-slot ring x (A+B) K-half chunks = 3 x 32 KB = 96 KB.
// Chunk = [256 rows][32 k] bf16 stored as 128 lines x 128 B; line j holds
// rows {2j, 2j+1}; 16B piece (e=row&1, q=k-piece) at slot (4e+q)^(j&7).
// Enumerated: every wave-wide ds_read_b128 hits each bank-quad with exactly
// 2 lanes -> 2-way = free (m136). Stage: thread t fills pieces t, t+512
// (linear dest, inverse-permuted source; both-sides involution, rule 21).
// Phase (4 per K-tile; 64 total): { vmcnt(4); barrier; 8 ds_read (half h,
// m-sub ms); stage ONE chunk (2 gloads) of half h+2.5; lgkmcnt(0);
// sched_barrier; setprio(1); 16 MFMA; setprio(0) }.
// Ring/hazard proof: half h read at phases 2h,2h+1; A(h) staged at 2h-4,
// B(h) at 2h-3; vmcnt(4) at phase top leaves only stages from P-2,P-1
// outstanding -> stages <= P-3 complete -> A(h),B(h) landed. WAR: stage(P)
// targets slot freed at P-2, separated by barrier(P). Bootstrap: prologue
// stages A0,B0,A1,B1; P0's vmcnt(4) leaves exactly A0,B0 complete.
// EPI 0: QKV epilogue (unswapped). EPI 1: scores (swapped, exp causal+rowsum).
// acc[i][j] i = ms*4+ii -> row offset i*16: identical layout to R8 epilogues.
// ---------------------------------------------------------------------------
template<int EPI>
__global__ __launch_bounds__(512, 2) void gemmf(
    const unsigned short* __restrict__ Ag, const unsigned short* __restrict__ Bg,
    void* __restrict__ P0, void* __restrict__ P1, void* __restrict__ P2,
    float* __restrict__ rowsum, float qscale)
{
    __shared__ __align__(16) unsigned short lds[49152];   // 96 KB: slot s at s*16384 (A +0, B +8192)

    int m0, n0, ntl = 0, z = 0;
    const unsigned short* A;
    const unsigned short* Bm;

    if (EPI == 0) {
        // 384 blocks = 8 XCDs x 48, bijective, mt-major per XCD.
        const int bid = blockIdx.x;
        const int wg  = (bid & 7) * 48 + (bid >> 3);
        const int mt  = wg / 12; ntl = wg - mt * 12;
        m0 = mt * 256; n0 = ntl * 256;
        A = Ag; Bm = Bg;
    } else {
        // lower-tri 256x256 tiles: f = ti(ti+1)/2 + tj, f in 0..35
        z = blockIdx.z;
        const int f = blockIdx.x;
        int ti = (int)((sqrtf(8.f * f + 1.f) - 1.f) * 0.5f);
        while ((ti + 1) * (ti + 2) / 2 <= f) ti++;
        while (ti * (ti + 1) / 2 > f) ti--;
        const int tj = f - ti * (ti + 1) / 2;
        m0 = ti * 256; n0 = tj * 256;
        A = Ag + (size_t)z * SEQ * DM; Bm = Bg + (size_t)z * SEQ * DM;
    }

    const int t    = threadIdx.x;
    const int w    = t >> 6;               // wave 0..7
    const int lane = t & 63;
    const int wr   = w >> 2, wc = w & 3;   // 2M x 4N, wave tile 128x64
    const int r    = lane & 15, q = lane >> 4;

    // read constants: slot8 = (4*(r&1)+q) ^ ((r>>1)&7)  (constant across frags)
    const int slot8 = ((4 * (r & 1) + q) ^ ((r >> 1) & 7)) * 8;   // shorts
    const int aOff  = wr * 4096 + (r >> 1) * 64 + slot8;          // + ms*2048 + ii*512
    const int bOff  = 8192 + wc * 2048 + (r >> 1) * 64 + slot8;   // + j*512

    // stage constants: thread t -> pieces t, t+512; x = (t&7)^((t>>3)&7)
    const int sx   = (t & 7) ^ ((t >> 3) & 7);
    const int sRow = 2 * (t >> 3) + ((sx >> 2) & 1);   // source row in chunk (g=0)
    const int sK   = (sx & 3) * 8;                      // source k offset within half

    floatx4 acc[8][4];
#pragma unroll
    for (int i = 0; i < 8; i++)
#pragma unroll
        for (int j = 0; j < 4; j++)
            acc[i][j] = (floatx4){0.f, 0.f, 0.f, 0.f};

    // stage chunk of K-half H (A or B operand) into ring slot SL (0/1/2)
#define STG_A(H, SL) do { \
    const int kb_ = (((H) < 32) ? (H) * 32 : 0) + sK; \
    gload16(A + (((size_t)(m0 + sRow))       << 10) + kb_, &lds[(SL) * 16384 + w * 512]); \
    gload16(A + (((size_t)(m0 + sRow + 128)) << 10) + kb_, &lds[(SL) * 16384 + w * 512 + 4096]); \
  } while (0)
#define STG_B(H, SL) do { \
    const int kb_ = (((H) < 32) ? (H) * 32 : 0) + sK; \
    gload16(Bm + (((size_t)(n0 + sRow))       << 10) + kb_, &lds[(SL) * 16384 + 8192 + w * 512]); \
    gload16(Bm + (((size_t)(n0 + sRow + 128)) << 10) + kb_, &lds[(SL) * 16384 + 8192 + w * 512 + 4096]); \
  } while (0)

#define ONE_MFMA(AC, AF, BF) do { \
    if (EPI == 0) (AC) = __builtin_amdgcn_mfma_f32_16x16x32_bf16((AF), (BF), (AC), 0, 0, 0); \
    else          (AC) = __builtin_amdgcn_mfma_f32_16x16x32_bf16((BF), (AF), (AC), 0, 0, 0); \
  } while (0)

    // one phase: K-half in ring slot SL, m-sub MS; stage via STG_EXPR
#define PHASE(SL, MS, STG_EXPR) do { \
    asm volatile("s_waitcnt vmcnt(4)" ::: "memory"); \
    __builtin_amdgcn_s_barrier(); \
    const int ab = (SL) * 16384 + aOff + (MS) * 2048; \
    const int bb = (SL) * 16384 + bOff; \
    short8 af0 = *(const short8*)&lds[ab +    0]; \
    short8 af1 = *(const short8*)&lds[ab +  512]; \
    short8 af2 = *(const short8*)&lds[ab + 1024]; \
    short8 af3 = *(const short8*)&lds[ab + 1536]; \
    short8 bf0 = *(const short8*)&lds[bb +    0]; \
    short8 bf1 = *(const short8*)&lds[bb +  512]; \
    short8 bf2 = *(const short8*)&lds[bb + 1024]; \
    short8 bf3 = *(const short8*)&lds[bb + 1536]; \
    STG_EXPR; \
    asm volatile("s_waitcnt lgkmcnt(0)" ::: "memory"); \
    __builtin_amdgcn_sched_barrier(0); \
    __builtin_amdgcn_s_setprio(1); \
    ONE_MFMA(acc[(MS)*4+0][0], af0, bf0); ONE_MFMA(acc[(MS)*4+0][1], af0, bf1); \
    ONE_MFMA(acc[(MS)*4+0][2], af0, bf2); ONE_MFMA(acc[(MS)*4+0][3], af0, bf3); \
    ONE_MFMA(acc[(MS)*4+1][0], af1, bf0); ONE_MFMA(acc[(MS)*4+1][1], af1, bf1); \
    ONE_MFMA(acc[(MS)*4+1][2], af1, bf2); ONE_MFMA(acc[(MS)*4+1][3], af1, bf3); \
    ONE_MFMA(acc[(MS)*4+2][0], af2, bf0); ONE_MFMA(acc[(MS)*4+2][1], af2, bf1); \
    ONE_MFMA(acc[(MS)*4+2][2], af2, bf2); ONE_MFMA(acc[(MS)*4+2][3], af2, bf3); \
    ONE_MFMA(acc[(MS)*4+3][0], af3, bf0); ONE_MFMA(acc[(MS)*4+3][1], af3, bf1); \
    ONE_MFMA(acc[(MS)*4+3][2], af3, bf2); ONE_MFMA(acc[(MS)*4+3][3], af3, bf3); \
    __builtin_amdgcn_s_setprio(0); \
  } while (0)

    // prologue: stage halves 0 and 1 (A0,B0,A1,B1 = 8 loads); P0's vmcnt(4)
    // then leaves exactly A0,B0 complete (counted bootstrap).
    STG_A(0, 0);
    STG_B(0, 0);
    STG_A(1, 1);
    STG_B(1, 1);

    // 16 K-tiles x 4 phases; ring slots: tile T uses s0=(2T)%3, s1=(s0+1)%3;
    // stages: ph0 A(2T+2)->s2, ph1 B(2T+2)->s2, ph2 A(2T+3)->s0, ph3 B(2T+3)->s0.
    int s0 = 0;
    for (int T = 0; T < 16; ++T) {
        const int s1 = (s0 + 1 == 3) ? 0 : s0 + 1;
        const int s2 = (s1 + 1 == 3) ? 0 : s1 + 1;
        const int h2 = 2 * T + 2, h3 = 2 * T + 3;
        PHASE(s0, 0, STG_A(h2, s2));
        PHASE(s0, 1, STG_B(h2, s2));
        PHASE(s1, 0, STG_A(h3, s0));
        PHASE(s1, 1, STG_B(h3, s0));
        s0 = s2;   // (s0+2)%3
    }
#undef PHASE
#undef STG_A
#undef STG_B
#undef ONE_MFMA

    // ------------------------- epilogues (R8-verified, identical acc layout) --
    if (EPI == 0) {
        // unswapped: row = m0 + wr*128 + i*16 + q*4 + rr, col = n0 + wc*64 + j*16 + r
        const int gmb = m0 + wr * 128 + q * 4;
        const int gnb = n0 + wc * 64 + r;
        unsigned short* Qo  = (unsigned short*)P0;
        unsigned short* Ko  = (unsigned short*)P1;
        unsigned short* Vto = (unsigned short*)P2;
        if (ntl < 4) {
#pragma unroll
            for (int i = 0; i < 8; i++) {
                const int gm = gmb + i * 16;
#pragma unroll
                for (int j = 0; j < 4; j++) {
                    const int gn = gnb + j * 16;
#pragma unroll
                    for (int rr = 0; rr < 4; rr++)
                        Qo[(size_t)(gm + rr) * 1024 + gn] = f2b(acc[i][j][rr] * qscale);
                }
            }
        } else if (ntl < 8) {
#pragma unroll
            for (int i = 0; i < 8; i++) {
                const int gm = gmb + i * 16;
#pragma unroll
                for (int j = 0; j < 4; j++) {
                    const int gn = gnb + j * 16;
#pragma unroll
                    for (int rr = 0; rr < 4; rr++)
                        Ko[(size_t)(gm + rr) * 1024 + (gn - 1024)] = f2b(acc[i][j][rr]);
                }
            }
        } else {
#pragma unroll
            for (int i = 0; i < 8; i++) {
                const int gm = gmb + i * 16;
                const int b  = gm >> 11;
                const int s  = gm & 2047;          // 4 consecutive tokens via rr
#pragma unroll
                for (int j = 0; j < 4; j++) {
                    const int v = gnb + j * 16 - 2048;
                    *(ushort4*)&Vto[((size_t)(b * 1024 + v)) * 2048 + s] =
                        pack4(acc[i][j][0], acc[i][j][1], acc[i][j][2], acc[i][j][3]);
                }
            }
        }
    } else {
        // swapped: row gm = m0 + wr*128 + i*16 + r, col gn = n0 + wc*64 + j*16 + q*4 + rr
        const int gmb = m0 + wr * 128 + r;
        const int gnb = n0 + wc * 64 + q * 4;
        unsigned short* E = (unsigned short*)P0 + (size_t)z * SEQ * SEQ;
        float* rs = rowsum + (size_t)z * SEQ;
#pragma unroll
        for (int i = 0; i < 8; i++) {
            const int gm = gmb + i * 16;
            float part = 0.f;
#pragma unroll
            for (int j = 0; j < 4; j++) {
                const int gn = gnb + j * 16;
                float e0 = (gn + 0 <= gm) ? __expf(acc[i][j][0]) : 0.f;
                float e1 = (gn + 1 <= gm) ? __expf(acc[i][j][1]) : 0.f;
                float e2 = (gn + 2 <= gm) ? __expf(acc[i][j][2]) : 0.f;
                float e3 = (gn + 3 <= gm) ? __expf(acc[i][j][3]) : 0.f;
                part += (e0 + e1) + (e2 + e3);
                *(ushort4*)&E[(size_t)gm * SEQ + gn] = pack4(e0, e1, e2, e3);
            }
            part += __shfl_xor(part, 16, 64);
            part += __shfl_xor(part, 32, 64);
            if (q == 0) atomicAdd(&rs[gm], part);
        }
    }
}

// ---------------------------------------------------------------------------
// PV GEMM (R5/R8 measured kernel, verbatim): BM=256, BN=128, BK=64, 8 waves
// 4Mx2N, ring-3 (144 KB), vmcnt(6), R0 zero-conflict chunks, one barrier per
// K-tile, swapped operands. C = E*Vt^T / rowsum; kEnd = m0+256, heavy-first.
// ---------------------------------------------------------------------------
#define SLOTS 24576

__global__ __launch_bounds__(512, 2) void attn_pv(
    const unsigned short* __restrict__ Ag, const unsigned short* __restrict__ Bg,
    float* __restrict__ Cv, const float* __restrict__ rowsum)
{
    __shared__ __align__(16) unsigned short lds[3 * SLOTS];   // 144 KB

    const int z = blockIdx.z;
    const int m0 = (int)(gridDim.y - 1 - blockIdx.y) * 256;   // heavy first
    const int n0 = blockIdx.x * 128;

    const unsigned short* A  = Ag + (size_t)z * SEQ * SEQ;
    const unsigned short* Bm = Bg + (size_t)z * DM * SEQ;
    const int NT = (m0 + 256) / 64;

    const int t    = threadIdx.x;
    const int w    = t >> 6;
    const int lane = t & 63;
    const int wr   = w >> 1, wc = w & 1;
    const int r    = lane & 15, q = lane >> 4;

    const int srow = lane >> 3;
    const int scol = ((lane & 7) ^ srow) << 3;

    const int aoff = (wr >> 1) * 8192 + ((wr & 1) * 64 + r) * 64;
    const int boff = 16384 + (wc * 64 + r) * 64;
    const int sk0  = ((0 + q) ^ (r & 7)) * 8;
    const int sk1  = ((4 + q) ^ (r & 7)) * 8;

    floatx4 acc[4][4];
#pragma unroll
    for (int i = 0; i < 4; i++)
#pragma unroll
        for (int j = 0; j < 4; j++)
            acc[i][j] = (floatx4){0.f, 0.f, 0.f, 0.f};

#define ASTG(KB, SL) do { \
    gload16(A + (size_t)(m0 +       w * 16 + srow) * SEQ + (KB) + scol, &lds[(SL) +         w * 1024]); \
    gload16(A + (size_t)(m0 +   8 + w * 16 + srow) * SEQ + (KB) + scol, &lds[(SL) +         w * 1024 + 512]); \
    gload16(A + (size_t)(m0 + 128 + w * 16 + srow) * SEQ + (KB) + scol, &lds[(SL) + 8192 +  w * 1024]); \
    gload16(A + (size_t)(m0 + 136 + w * 16 + srow) * SEQ + (KB) + scol, &lds[(SL) + 8192 +  w * 1024 + 512]); \
  } while (0)
#define BSTG(KB, SL) do { \
    gload16(Bm + (size_t)(n0 +      w * 16 + srow) * SEQ + (KB) + scol, &lds[(SL) + 16384 + w * 1024]); \
    gload16(Bm + (size_t)(n0 +  8 + w * 16 + srow) * SEQ + (KB) + scol, &lds[(SL) + 16384 + w * 1024 + 512]); \
  } while (0)

    ASTG(0, 0);
    BSTG(0, 0);
    ASTG(64, SLOTS);
    BSTG(64, SLOTS);
    asm volatile("s_waitcnt vmcnt(6)" ::: "memory");
    __builtin_amdgcn_s_barrier();

    for (int tt = 0; tt < NT; ++tt) {
        const int sl  = (tt % 3) * SLOTS;
        const int nsl = ((tt + 2) % 3) * SLOTS;
        const int nkb = (tt + 2 < NT) ? (tt + 2) * 64 : 0;

        const int aB = sl + aoff;
        const int bB = sl + boff;
        short8 a00 = *(const short8*)&lds[aB + sk0 +    0];
        short8 a10 = *(const short8*)&lds[aB + sk0 + 1024];
        short8 a20 = *(const short8*)&lds[aB + sk0 + 2048];
        short8 a30 = *(const short8*)&lds[aB + sk0 + 3072];
        short8 b00 = *(const short8*)&lds[bB + sk0 +    0];
        short8 b10 = *(const short8*)&lds[bB + sk0 + 1024];
        short8 b20 = *(const short8*)&lds[bB + sk0 + 2048];
        short8 b30 = *(const short8*)&lds[bB + sk0 + 3072];
        short8 a01 = *(const short8*)&lds[aB + sk1 +    0];
        short8 a11 = *(const short8*)&lds[aB + sk1 + 1024];
        short8 a21 = *(const short8*)&lds[aB + sk1 + 2048];
        short8 a31 = *(const short8*)&lds[aB + sk1 + 3072];
        short8 b01 = *(const short8*)&lds[bB + sk1 +    0];
        short8 b11 = *(const short8*)&lds[bB + sk1 + 1024];
        short8 b21 = *(const short8*)&lds[bB + sk1 + 2048];
        short8 b31 = *(const short8*)&lds[bB + sk1 + 3072];

        ASTG(nkb, nsl);
        BSTG(nkb, nsl);
        asm volatile("s_waitcnt vmcnt(6)" ::: "memory");
        __builtin_amdgcn_s_barrier();

        __builtin_amdgcn_s_setprio(1);
        acc[0][0] = __builtin_amdgcn_mfma_f32_16x16x32_bf16(b00, a00, acc[0][0], 0, 0, 0);
        acc[0][1] = __builtin_amdgcn_mfma_f32_16x16x32_bf16(b10, a00, acc[0][1], 0, 0, 0);
        acc[0][2] = __builtin_amdgcn_mfma_f32_16x16x32_bf16(b20, a00, acc[0][2], 0, 0, 0);
        acc[0][3] = __builtin_amdgcn_mfma_f32_16x16x32_bf16(b30, a00, acc[0][3], 0, 0, 0);
        acc[1][0] = __builtin_amdgcn_mfma_f32_16x16x32_bf16(b00, a10, acc[1][0], 0, 0, 0);
        acc[1][1] = __builtin_amdgcn_mfma_f32_16x16x32_bf16(b10, a10, acc[1][1], 0, 0, 0);
        acc[1][2] = __builtin_amdgcn_mfma_f32_16x16x32_bf16(b20, a10, acc[1][2], 0, 0, 0);
        acc[1][3] = __builtin_amdgcn_mfma_f32_16x16x32_bf16(b30, a10, acc[1][3], 0, 0, 0);
        acc[2][0] = __builtin_amdgcn_mfma_f32_16x16x32_bf16(b00, a20, acc[2][0], 0, 0, 0);
        acc[2][1] = __builtin_amdgcn_mfma_f32_16x16x32_bf16(b10, a20, acc[2][1], 0, 0, 0);
        acc[2][2] = __builtin_amdgcn_mfma_f32_16x16x32_bf16(b20, a20, acc[2][2], 0, 0, 0);
        acc[2][3] = __builtin_amdgcn_mfma_f32_16x16x32_bf16(b30, a20, acc[2][3], 0, 0, 0);
        acc[3][0] = __builtin_amdgcn_mfma_f32_16x16x32_bf16(b00, a30, acc[3][0], 0, 0, 0);
        acc[3][1] = __builtin_amdgcn_mfma_f32_16x16x32_bf16(b10, a30, acc[3][1], 0, 0, 0);
        acc[3][2] = __builtin_amdgcn_mfma_f32_16x16x32_bf16(b20, a30, acc[3][2], 0, 0, 0);
        acc[3][3] = __builtin_amdgcn_mfma_f32_16x16x32_bf16(b30, a30, acc[3][3], 0, 0, 0);
        acc[0][0] = __builtin_amdgcn_mfma_f32_16x16x32_bf16(b01, a01, acc[0][0], 0, 0, 0);
        acc[0][1] = __builtin_amdgcn_mfma_f32_16x16x32_bf16(b11, a01, acc[0][1], 0, 0, 0);
        acc[0][2] = __builtin_amdgcn_mfma_f32_16x16x32_bf16(b21, a01, acc[0][2], 0, 0, 0);
        acc[0][3] = __builtin_amdgcn_mfma_f32_16x16x32_bf16(b31, a01, acc[0][3], 0, 0, 0);
        acc[1][0] = __builtin_amdgcn_mfma_f32_16x16x32_bf16(b01, a11, acc[1][0], 0, 0, 0);
        acc[1][1] = __builtin_amdgcn_mfma_f32_16x16x32_bf16(b11, a11, acc[1][1], 0, 0, 0);
        acc[1][2] = __builtin_amdgcn_mfma_f32_16x16x32_bf16(b21, a11, acc[1][2], 0, 0, 0);
        acc[1][3] = __builtin_amdgcn_mfma_f32_16x16x32_bf16(b31, a11, acc[1][3], 0, 0, 0);
        acc[2][0] = __builtin_amdgcn_mfma_f32_16x16x32_bf16(b01, a21, acc[2][0], 0, 0, 0);
        acc[2][1] = __builtin_amdgcn_mfma_f32_16x16x32_bf16(b11, a21, acc[2][1], 0, 0, 0);
        acc[2][2] = __builtin_amdgcn_mfma_f32_16x16x32_bf16(b21, a21, acc[2][2], 0, 0, 0);
        acc[2][3] = __builtin_amdgcn_mfma_f32_16x16x32_bf16(b31, a21, acc[2][3], 0, 0, 0);
        acc[3][0] = __builtin_amdgcn_mfma_f32_16x16x32_bf16(b01, a31, acc[3][0], 0, 0, 0);
        acc[3][1] = __builtin_amdgcn_mfma_f32_16x16x32_bf16(b11, a31, acc[3][1], 0, 0, 0);
        acc[3][2] = __builtin_amdgcn_mfma_f32_16x16x32_bf16(b21, a31, acc[3][2], 0, 0, 0);
        acc[3][3] = __builtin_amdgcn_mfma_f32_16x16x32_bf16(b31, a31, acc[3][3], 0, 0, 0);
        __builtin_amdgcn_s_setprio(0);
    }
#undef ASTG
#undef BSTG

    // swapped epilogue: row gm = m0 + wr*64 + i*16 + r, col gn = n0 + wc*64 + j*16 + q*4 + rr
    const int gmb = m0 + wr * 64 + r;
    const int gnb = n0 + wc * 64 + q * 4;
    float* C = Cv + (size_t)z * SEQ * DM;
    const float* rs = rowsum + (size_t)z * SEQ;
#pragma unroll
    for (int i = 0; i < 4; i++) {
        const int gm = gmb + i * 16;
        const float inv = 1.0f / rs[gm];
#pragma unroll
        for (int j = 0; j < 4; j++) {
            const int gn = gnb + j * 16;
            float4 o;
            o.x = acc[i][j][0] * inv;
            o.y = acc[i][j][1] * inv;
            o.z = acc[i][j][2] * inv;
            o.w = acc[i][j][3] * inv;
            *(float4*)&C[(size_t)gm * DM + gn] = o;
        }
    }
}

extern "C" void kernel_launch(void* const* d_in, const int* in_sizes, int n_in,
                              void* d_out, int out_size, void* d_ws, size_t ws_size,
                              hipStream_t stream) {
    (void)in_sizes; (void)n_in; (void)out_size; (void)ws_size;
    const float* x  = (const float*)d_in[0];
    // d_in[1] = mask (causal; implicit — unused)
    const float* Wq = (const float*)d_in[2];
    const float* Wk = (const float*)d_in[3];
    const float* Wv = (const float*)d_in[4];

    char* base = (char*)d_ws;
    size_t off = 0;
    auto alloc = [&](size_t n) { char* p = base + off; off += (n + 255) & ~(size_t)255; return p; };

    unsigned short* xb   = (unsigned short*)alloc((size_t)NBAT * SEQ * DM * 2);  // 16.8 MB
    unsigned short* wall = (unsigned short*)alloc((size_t)3 * DM * DM * 2);      // 6.3 MB
    unsigned short* Qb   = (unsigned short*)alloc((size_t)NBAT * SEQ * DM * 2);  // scaled 1/32
    unsigned short* Kb   = (unsigned short*)alloc((size_t)NBAT * SEQ * DM * 2);
    unsigned short* Vtb  = (unsigned short*)alloc((size_t)NBAT * DM * SEQ * 2);  // [b][v][s]
    unsigned short* E    = (unsigned short*)alloc((size_t)NBAT * SEQ * SEQ * 2); // 33.5 MB
    float*          rsum = (float*)alloc((size_t)NBAT * SEQ * 4);

    // 1) fused prep: casts + rowsum zero (11296 blocks)
    prep<<<dim3(11296), dim3(256), 0, stream>>>(
        (const float4*)x, (const float4*)Wq, (const float4*)Wk, (const float4*)Wv,
        (ushort4*)xb, (ushort4*)wall, rsum);

    // 2) fused QKV projection: fine-phase 256^2 core; 32x12 = 384 blocks
    gemmf<0><<<dim3(384), dim3(512), 0, stream>>>(
        xb, wall, Qb, Kb, Vtb, nullptr, 0.03125f);

    // 3) E = exp(Q K^T) causal + rowsum: 36 tri-tiles x 4 batches = 144 blocks (1 round)
    gemmf<1><<<dim3(36, 1, NBAT), dim3(512), 0, stream>>>(
        Qb, Kb, E, nullptr, nullptr, rsum, 0.f);

    // 4) out = (E Vt^T)/rowsum: 8x8x4 = 256 blocks (1 round), heavy-first (R5 kernel)
    attn_pv<<<dim3(DM / 128, SEQ / 256, NBAT), dim3(512), 0, stream>>>(
        E, Vtb, (float*)d_out, rsum);
}